// Round 7
// baseline (208.390 us; speedup 1.0000x reference)
//
#include <hip/hip_runtime.h>

#define EPS 1e-3f
#define NPIX  50176   // 16*56*56
#define NOPIX 12544   // 16*28*28

// ws float offsets
#define OFF_ST1  0        // [32][128][2] (s,t) for bn1
#define OFF_S2   8192     // [32][4]
#define OFF_T2   8320     // [32][4]
#define OFF_T3   8448     // [128]
#define OFF_BSUM 8576     // [256]
#define OFF_W3S  8832     // [32 g][4 f][9 kk][4 ci] pre-scaled by s3
#define OFF_U    13440    // [32 g][50176 px] ushort4 (bf16, g-planar)

__device__ __forceinline__ unsigned short f2bf(float f) {
    unsigned u = __float_as_uint(f);
    return (unsigned short)((u + 0x7fffu + ((u >> 16) & 1u)) >> 16);
}
__device__ __forceinline__ float bf2f(unsigned short s) {
    return __uint_as_float(((unsigned)s) << 16);
}

__global__ __launch_bounds__(256)
void prep_kernel(const float* __restrict__ g1, const float* __restrict__ be1,
                 const float* __restrict__ m1, const float* __restrict__ v1,
                 const float* __restrict__ b1, const float* __restrict__ g2,
                 const float* __restrict__ be2, const float* __restrict__ m2,
                 const float* __restrict__ v2, const float* __restrict__ W3,
                 const float* __restrict__ b3, const float* __restrict__ g3,
                 const float* __restrict__ be3, const float* __restrict__ m3,
                 const float* __restrict__ v3, const float* __restrict__ b2,
                 float* __restrict__ ws) {
    int gid = blockIdx.x * 256 + threadIdx.x;
    int stride = gridDim.x * 256;
    for (int i = gid; i < 4096; i += stride) {
        float s = g1[i] * rsqrtf(v1[i] + EPS);
        float t = be1[i] - m1[i] * s;
        ws[OFF_ST1 + 2*i]     = s;
        ws[OFF_ST1 + 2*i + 1] = t;
    }
    // W3 re-laid f-major, pre-scaled by s3: [g][f][kk][ci]
    for (int i = gid; i < 4608; i += stride) {
        int g = i / 144, rem = i - g*144;
        int f = rem / 36, rem2 = rem - f*36;
        int kk = rem2 >> 2, ci = rem2 & 3;
        int k = g*4 + f;
        float s3 = g3[k] * rsqrtf(v3[k] + EPS);
        ws[OFF_W3S + i] = W3[g*144 + kk*16 + ci*4 + f] * s3;
    }
    if (gid < 128) {
        float s2 = g2[gid] * rsqrtf(v2[gid] + EPS);
        ws[OFF_S2 + gid] = s2;
        ws[OFF_T2 + gid] = be2[gid] + (b1[gid] - m2[gid]) * s2;
        float s3 = g3[gid] * rsqrtf(v3[gid] + EPS);
        ws[OFF_T3 + gid] = be3[gid] + (b3[gid] - m3[gid]) * s3;
    } else if (gid >= 256 && gid < 512) {
        int co = gid - 256;
        float acc = 0.f;
        for (int g = 0; g < 32; ++g) acc += b2[g*256 + co];
        ws[OFF_BSUM + co] = acc;
    }
}

// Stage 1: block 512 = 8 waves over the same 64 px; wave w owns groups
// [4w,4w+4). Channel halves of 64: hoist x into xr[64] regs (one lgkm drain
// per half), then PURE s_load+VALU inner loop (no ds/s_load mixing).
// U stored g-planar bf16: 512 B contiguous per wave-store.
__global__ __launch_bounds__(512, 4)
void stage1_kernel(const float* __restrict__ x,
                   const float* __restrict__ W1,     // [32,128,4]
                   const float* __restrict__ tabs,   // ws
                   float* __restrict__ uout) {       // ws + OFF_U
    __shared__ float4 xs4[2048];                     // 32 KB, XOR-swizzled
    int tid = threadIdx.x;
    const float4* xg = (const float4*)x + (size_t)blockIdx.x * 2048;
    for (int i = tid; i < 2048; i += 512) {
        int p = i >> 5, f4 = i & 31;
        xs4[p*32 + (f4 ^ (p & 31))] = xg[i];
    }
    __syncthreads();

    int lane = tid & 63;
    int wbase = __builtin_amdgcn_readfirstlane(tid >> 6) * 4;   // 0..28

    float acc[4][4];
    #pragma unroll
    for (int gi = 0; gi < 4; ++gi)
        acc[gi][0] = acc[gi][1] = acc[gi][2] = acc[gi][3] = 0.f;

    #pragma unroll 1
    for (int h = 0; h < 2; ++h) {
        float xr[64];
        #pragma unroll
        for (int j = 0; j < 16; ++j)
            *(float4*)&xr[4*j] = xs4[lane*32 + ((h*16 + j) ^ (lane & 31))];
        #pragma unroll
        for (int gi = 0; gi < 4; ++gi) {
            int g = wbase + gi;
            const float2* st = (const float2*)(tabs + OFF_ST1) + g*128 + h*64;
            const float4* w1 = (const float4*)W1 + g*128 + h*64;
            #pragma unroll
            for (int c = 0; c < 64; ++c) {
                float2 s = st[c];          // uniform -> s_load
                float4 w = w1[c];          // uniform -> s_load
                float z = fmaxf(fmaf(xr[c], s.x, s.y), 0.f);
                acc[gi][0] = fmaf(z, w.x, acc[gi][0]);
                acc[gi][1] = fmaf(z, w.y, acc[gi][1]);
                acc[gi][2] = fmaf(z, w.z, acc[gi][2]);
                acc[gi][3] = fmaf(z, w.w, acc[gi][3]);
            }
        }
    }

    ushort4* U4 = (ushort4*)uout;
    size_t pxIdx = (size_t)blockIdx.x * 64 + lane;
    #pragma unroll
    for (int gi = 0; gi < 4; ++gi) {
        int g = wbase + gi;
        float4 s2v = ((const float4*)(tabs + OFF_S2))[g];
        float4 t2v = ((const float4*)(tabs + OFF_T2))[g];
        ushort4 o;
        o.x = f2bf(fmaxf(fmaf(acc[gi][0], s2v.x, t2v.x), 0.f));
        o.y = f2bf(fmaxf(fmaf(acc[gi][1], s2v.y, t2v.y), 0.f));
        o.z = f2bf(fmaxf(fmaf(acc[gi][2], s2v.z, t2v.z), 0.f));
        o.w = f2bf(fmaxf(fmaf(acc[gi][3], s2v.w, t2v.w), 0.f));
        U4[(size_t)g * NPIX + pxIdx] = o;  // 512 B contiguous per wave
    }
}

// Stage 2: block = 16 opx, 512 threads, grid 784.
// Conv: thread = (oct=tid>>6, opx_l=(tid>>2)&15, f=tid&3), 4 g per thread.
// Residual: 16 px x 32 lanes. GEMM: thread = 2 opx x 4 co.
__global__ __launch_bounds__(512, 4)
void stage2_kernel(const float* __restrict__ x,
                   const float* __restrict__ W2,     // [128,256]
                   const float* __restrict__ tabs,   // ws
                   const float* __restrict__ U,      // ws + OFF_U (bf16)
                   float* __restrict__ out) {
    __shared__ float w3s[4608];
    __shared__ float t3s[128];
    __shared__ float vs[16 * 132];
    __shared__ float res_s[16];
    int tid = threadIdx.x;
    for (int i = tid; i < 4608; i += 512) w3s[i] = tabs[OFF_W3S + i];
    if (tid < 128) t3s[tid] = tabs[OFF_T3 + tid];
    __syncthreads();

    int opxBase = blockIdx.x * 16;
    // ---- 3x3 stride-2 conv ----
    {
        int oct = tid >> 6, opx_l = (tid >> 2) & 15, f = tid & 3;
        int opx = opxBase + opx_l;
        int b = opx / 784, r = opx - b*784;
        int oh = r / 28, ow = r - oh*28;
        #pragma unroll 1
        for (int gi = 0; gi < 4; ++gi) {
            int g = oct*4 + gi;
            const ushort4* Ug = (const ushort4*)U + (size_t)g * NPIX;
            const float* wg = w3s + g*144 + f*36;
            float a = 0.f;
            #pragma unroll
            for (int kh = 0; kh < 3; ++kh) {
                int ih = 2*oh - 1 + kh;
                if (ih < 0) continue;
                #pragma unroll
                for (int kw = 0; kw < 3; ++kw) {
                    int ic = 2*ow - 1 + kw;
                    if (ic < 0) continue;
                    ushort4 u = Ug[(b*56 + ih)*56 + ic];
                    float4 wv = *(const float4*)(wg + (kh*3 + kw)*4);
                    a = fmaf(bf2f(u.x), wv.x, a);
                    a = fmaf(bf2f(u.y), wv.y, a);
                    a = fmaf(bf2f(u.z), wv.z, a);
                    a = fmaf(bf2f(u.w), wv.w, a);
                }
            }
            int k = g*4 + f;
            vs[opx_l*132 + k] = fmaxf(a + t3s[k], 0.f);
        }
    }
    // ---- residual: res[p] = sum_c x[b, 2oh, 2ow, c] ----
    {
        int p = tid >> 5, l = tid & 31;
        int opx = opxBase + p;
        int b = opx / 784, r = opx - b*784;
        int oh = r / 28, ow = r - oh*28;
        const float* xp = x + (size_t)((b*56 + 2*oh)*56 + 2*ow) * 128;
        float rv = xp[l] + xp[l+32] + xp[l+64] + xp[l+96];
        #pragma unroll
        for (int off = 16; off; off >>= 1) rv += __shfl_down(rv, off, 32);
        if (l == 0) res_s[p] = rv;
    }
    __syncthreads();

    // ---- phase B: out[opx][co] = vs @ W2 + bsum + res ----
    int w = tid >> 6, l = tid & 63;
    float4 bs = *(const float4*)(tabs + OFF_BSUM + 4*l);
    float acc[2][4];
    #pragma unroll
    for (int q = 0; q < 2; ++q) {
        acc[q][0] = bs.x; acc[q][1] = bs.y;
        acc[q][2] = bs.z; acc[q][3] = bs.w;
    }
    const float* W2c = W2 + 4*l;
    #pragma unroll 2
    for (int k4 = 0; k4 < 32; ++k4) {
        float4 wr0 = *(const float4*)(W2c + (k4*4 + 0)*256);
        float4 wr1 = *(const float4*)(W2c + (k4*4 + 1)*256);
        float4 wr2 = *(const float4*)(W2c + (k4*4 + 2)*256);
        float4 wr3 = *(const float4*)(W2c + (k4*4 + 3)*256);
        #pragma unroll
        for (int q = 0; q < 2; ++q) {
            float4 v = *(const float4*)&vs[(w*2 + q)*132 + k4*4];  // broadcast
            acc[q][0] = fmaf(v.x, wr0.x, acc[q][0]);
            acc[q][1] = fmaf(v.x, wr0.y, acc[q][1]);
            acc[q][2] = fmaf(v.x, wr0.z, acc[q][2]);
            acc[q][3] = fmaf(v.x, wr0.w, acc[q][3]);
            acc[q][0] = fmaf(v.y, wr1.x, acc[q][0]);
            acc[q][1] = fmaf(v.y, wr1.y, acc[q][1]);
            acc[q][2] = fmaf(v.y, wr1.z, acc[q][2]);
            acc[q][3] = fmaf(v.y, wr1.w, acc[q][3]);
            acc[q][0] = fmaf(v.z, wr2.x, acc[q][0]);
            acc[q][1] = fmaf(v.z, wr2.y, acc[q][1]);
            acc[q][2] = fmaf(v.z, wr2.z, acc[q][2]);
            acc[q][3] = fmaf(v.z, wr2.w, acc[q][3]);
            acc[q][0] = fmaf(v.w, wr3.x, acc[q][0]);
            acc[q][1] = fmaf(v.w, wr3.y, acc[q][1]);
            acc[q][2] = fmaf(v.w, wr3.z, acc[q][2]);
            acc[q][3] = fmaf(v.w, wr3.w, acc[q][3]);
        }
    }
    #pragma unroll
    for (int q = 0; q < 2; ++q) {
        float rq = res_s[w*2 + q];
        float4 o;
        o.x = acc[q][0] + rq; o.y = acc[q][1] + rq;
        o.z = acc[q][2] + rq; o.w = acc[q][3] + rq;
        *(float4*)(out + (size_t)(opxBase + w*2 + q)*256 + 4*l) = o;
    }
}

extern "C" void kernel_launch(void* const* d_in, const int* in_sizes, int n_in,
                              void* d_out, int out_size, void* d_ws, size_t ws_size,
                              hipStream_t stream) {
    const float* x   = (const float*)d_in[0];
    const float* g1  = (const float*)d_in[1];
    const float* be1 = (const float*)d_in[2];
    const float* m1  = (const float*)d_in[3];
    const float* v1  = (const float*)d_in[4];
    const float* W1  = (const float*)d_in[5];
    const float* b1  = (const float*)d_in[6];
    const float* g2  = (const float*)d_in[7];
    const float* be2 = (const float*)d_in[8];
    const float* m2  = (const float*)d_in[9];
    const float* v2  = (const float*)d_in[10];
    const float* W3  = (const float*)d_in[11];
    const float* b3  = (const float*)d_in[12];
    const float* g3  = (const float*)d_in[13];
    const float* be3 = (const float*)d_in[14];
    const float* m3  = (const float*)d_in[15];
    const float* v3  = (const float*)d_in[16];
    const float* W2  = (const float*)d_in[17];
    const float* b2  = (const float*)d_in[18];
    float* out = (float*)d_out;
    float* ws  = (float*)d_ws;

    prep_kernel<<<32, 256, 0, stream>>>(g1, be1, m1, v1, b1, g2, be2, m2, v2,
                                        W3, b3, g3, be3, m3, v3, b2, ws);
    stage1_kernel<<<NPIX / 64, 512, 0, stream>>>(x, W1, ws, ws + OFF_U);
    stage2_kernel<<<NOPIX / 16, 512, 0, stream>>>(x, W2, ws, ws + OFF_U, out);
}